// Round 5
// baseline (580.838 us; speedup 1.0000x reference)
//
#include <hip/hip_runtime.h>

// ---------------------------------------------------------------------------
// Kernel A: segment boundaries in SORTED domain_ids.
// starts[d]=-1 (memset 0xFF) means empty domain.
// ---------------------------------------------------------------------------
__global__ void bounds_kernel(const int* __restrict__ dids,
                              int* __restrict__ starts,
                              int* __restrict__ ends, int E) {
    int e = blockIdx.x * blockDim.x + threadIdx.x;
    if (e >= E) return;
    int d = dids[e];
    if (e == 0) {
        starts[d] = 0;
    } else {
        int dp = dids[e - 1];
        if (d != dp) {
            starts[d] = e;
            ends[dp]  = e;
        }
    }
    if (e == E - 1) ends[d] = E;
}

// ---------------------------------------------------------------------------
// Fused v6: gather+segment-sum+projection in ONE kernel. Deletes the 64 MB
// T intermediate (was: 62.5 MB HBM write + 64 MB HBM read + extra dispatch).
//
// Block = 256 threads = 4 waves, DPB=128 domains per block.
// Phase 1 (gather): wave w handles domains [row0+32w, row0+32w+32). Inner
//   loop is v4's proven structure, byte-identical accumulation order:
//   16-lane groups gather float4 feature rows, 4 entries per load phase,
//   batched index fetch + __shfl distribution, butterfly fold, lanes 0-15
//   hold the domain's 64 channels. Row written to lds_t[r][.] as b128
//   (banks 4*l16 -> 2-way aliasing = free).
// Phase 2 (GEMM): after one __syncthreads, v5-style 8x8 register blocking:
//   thread (tid) owns rows r0..r0+7 (r0=(tid>>4)*8), cols c0..c0+7
//   (c0=(tid&15)*8). Per k-quad: 8 b128 T-reads (16-lane broadcast, 4-way
//   across groups = 1.58x, hidden under FMA) + 8 b128 W-reads + 256 FMA
//   (512 cy) -> FMA-bound. Device FMA floor 26 us, overlapped with the
//   other resident block's gather.
// LDS: 32 KB (W) + 128*68*4 = 34 KB (T tile) = 66 KB -> 2 blocks/CU.
// Occupancy 8 waves/CU: in-flight gather bytes 8 waves * 4 KB = 32 KB/CU
// >> 3 KB needed at the measured 3.3 TB/s fabric gather ceiling.
// ---------------------------------------------------------------------------
#define DPB 128

#define KSTEP(J, COMP)                                               \
    {                                                                \
        float4 wa = *(const float4*)&lds_w[kq * 4 + J][c0];          \
        float4 wb = *(const float4*)&lds_w[kq * 4 + J][c0 + 4];      \
        _Pragma("unroll")                                            \
        for (int r = 0; r < 8; ++r) {                                \
            float tv = tr[r].COMP;                                   \
            acc[r][0] = fmaf(tv, wa.x, acc[r][0]);                   \
            acc[r][1] = fmaf(tv, wa.y, acc[r][1]);                   \
            acc[r][2] = fmaf(tv, wa.z, acc[r][2]);                   \
            acc[r][3] = fmaf(tv, wa.w, acc[r][3]);                   \
            acc[r][4] = fmaf(tv, wb.x, acc[r][4]);                   \
            acc[r][5] = fmaf(tv, wb.y, acc[r][5]);                   \
            acc[r][6] = fmaf(tv, wb.z, acc[r][6]);                   \
            acc[r][7] = fmaf(tv, wb.w, acc[r][7]);                   \
        }                                                            \
    }

__global__ void __launch_bounds__(256)
fused_kernel(const float* __restrict__ feat,
             const int* __restrict__ aidx,
             const int* __restrict__ starts,
             const int* __restrict__ ends,
             const float* __restrict__ W,
             const float* __restrict__ bias,
             float* __restrict__ out, int M) {
    __shared__ float lds_w[64][128];
    __shared__ float lds_t[DPB][68];      // row stride 272 B (16B mult)

    int tid  = threadIdx.x;
    long row0 = (long)blockIdx.x * DPB;

    // Stage W: 2048 float4, 8 per thread, coalesced (L3-hot after 1st block).
#pragma unroll
    for (int i = 0; i < 8; ++i) {
        int idx = tid + i * 256;          // 0..2047
        int k   = idx >> 5;
        int ch  = idx & 31;
        float4 wv = ((const float4*)W)[idx];
        *(float4*)&lds_w[k][ch * 4] = wv;
    }

    // ------------------ Phase 1: gather + segment-sum ------------------
    int wv_  = tid >> 6;                  // wave 0..3
    int lane = tid & 63;
    int g    = lane >> 4;                 // entry-phase group 0..3
    int l16  = lane & 15;                 // float4 chunk within the row
    int coff = l16 * 4;

    for (int i = 0; i < 32; ++i) {
        int  r = wv_ * 32 + i;            // row in tile 0..127
        long d = row0 + r;                // domain id
        float4 ga = make_float4(0.f, 0.f, 0.f, 0.f);
        if (d < M) {
            int s = starts[d];
            int e = ends[d];
            if (s >= 0) {
                int last = e - 1;
                for (int base = s; base < e; base += 16) {
                    int rem = e - base;            // uniform, >= 1
                    int ti  = base + l16;
                    int idxv = aidx[ti <= last ? ti : last];
                    if (rem >= 16) {
#pragma unroll
                        for (int p = 0; p < 4; ++p) {
                            int row = __shfl(idxv, p * 4 + g, 64);
                            const float4 v =
                                *(const float4*)(feat + (size_t)row * 64 + coff);
                            ga.x += v.x; ga.y += v.y; ga.z += v.z; ga.w += v.w;
                        }
                    } else {
                        int nph = (rem + 3) >> 2;  // uniform phase count
                        for (int p = 0; p < nph; ++p) {
                            int t   = base + p * 4 + g;
                            int row = __shfl(idxv, p * 4 + g, 64);
                            const float4 v =
                                *(const float4*)(feat + (size_t)row * 64 + coff);
                            float w = (t <= last) ? 1.f : 0.f;
                            ga.x = fmaf(v.x, w, ga.x);
                            ga.y = fmaf(v.y, w, ga.y);
                            ga.z = fmaf(v.z, w, ga.z);
                            ga.w = fmaf(v.w, w, ga.w);
                        }
                    }
                }
                ga.x += __shfl_xor(ga.x, 16, 64);
                ga.y += __shfl_xor(ga.y, 16, 64);
                ga.z += __shfl_xor(ga.z, 16, 64);
                ga.w += __shfl_xor(ga.w, 16, 64);
                ga.x += __shfl_xor(ga.x, 32, 64);
                ga.y += __shfl_xor(ga.y, 32, 64);
                ga.z += __shfl_xor(ga.z, 32, 64);
                ga.w += __shfl_xor(ga.w, 32, 64);
            }
        }
        if (g == 0)
            *(float4*)&lds_t[r][coff] = ga;
    }
    __syncthreads();

    // ------------------ Phase 2: 128x128 tile GEMM ------------------
    int c0 = (tid & 15) * 8;              // 8 output cols
    int r0 = (tid >> 4) * 8;              // 8 output rows

    float acc[8][8];
#pragma unroll
    for (int r = 0; r < 8; ++r)
#pragma unroll
        for (int c = 0; c < 8; ++c) acc[r][c] = 0.f;

#pragma unroll 2
    for (int kq = 0; kq < 16; ++kq) {
        float4 tr[8];
#pragma unroll
        for (int r = 0; r < 8; ++r)
            tr[r] = *(const float4*)&lds_t[r0 + r][kq * 4];
        KSTEP(0, x)
        KSTEP(1, y)
        KSTEP(2, z)
        KSTEP(3, w)
    }

    float4 bva = *(const float4*)&bias[c0];
    float4 bvb = *(const float4*)&bias[c0 + 4];
#pragma unroll
    for (int r = 0; r < 8; ++r) {
        long row = row0 + r0 + r;
        if (row < M) {
            float4 o0, o1;
            o0.x = acc[r][0] + bva.x;
            o0.y = acc[r][1] + bva.y;
            o0.z = acc[r][2] + bva.z;
            o0.w = acc[r][3] + bva.w;
            o1.x = acc[r][4] + bvb.x;
            o1.y = acc[r][5] + bvb.y;
            o1.z = acc[r][6] + bvb.z;
            o1.w = acc[r][7] + bvb.w;
            *(float4*)&out[row * 128 + c0]     = o0;
            *(float4*)&out[row * 128 + c0 + 4] = o1;
        }
    }
}

extern "C" void kernel_launch(void* const* d_in, const int* in_sizes, int n_in,
                              void* d_out, int out_size, void* d_ws, size_t ws_size,
                              hipStream_t stream) {
    const float* feat = (const float*)d_in[0];   // [N_ATOMS, 64] f32
    const int*   aidx = (const int*)d_in[1];     // [E] int
    const int*   dids = (const int*)d_in[2];     // [E] int (sorted)
    const float* W    = (const float*)d_in[4];   // [64, 128] f32
    const float* bias = (const float*)d_in[5];   // [128] f32
    float*       out  = (float*)d_out;           // [M, 128] f32

    int E = in_sizes[1];
    int M = out_size / 128;

    // Only boundary arrays in workspace now (T intermediate is gone).
    // Prior rounds proved ws_size >= 66 MB (T lived there); 2 MB is safe.
    size_t bbytes = 2 * (size_t)M * sizeof(int);
    int* starts = (int*)d_ws;
    int* ends   = starts + M;

    hipMemsetAsync(starts, 0xFF, bbytes, stream);

    bounds_kernel<<<(E + 255) / 256, 256, 0, stream>>>(dids, starts, ends, E);

    int nblocks = (M + DPB - 1) / DPB;
    fused_kernel<<<nblocks, 256, 0, stream>>>(feat, aidx, starts, ends,
                                              W, bias, out, M);
}

// Round 6
// 420.424 us; speedup vs baseline: 1.3816x; 1.3816x over previous
//
#include <hip/hip_runtime.h>
#include <hip/hip_fp16.h>

union H4 { uint2 u; __half h[4]; };

// ---------------------------------------------------------------------------
// Kernel A: segment boundaries in SORTED domain_ids.
// starts[d]=-1 (memset 0xFF) means empty domain.
// ---------------------------------------------------------------------------
__global__ void bounds_kernel(const int* __restrict__ dids,
                              int* __restrict__ starts,
                              int* __restrict__ ends, int E) {
    int e = blockIdx.x * blockDim.x + threadIdx.x;
    if (e >= E) return;
    int d = dids[e];
    if (e == 0) {
        starts[d] = 0;
    } else {
        int dp = dids[e - 1];
        if (d != dp) {
            starts[d] = e;
            ends[dp]  = e;
        }
    }
    if (e == E - 1) ends[d] = E;
}

// ---------------------------------------------------------------------------
// Conv: features f32 -> fp16 (once per launch). Streaming, ~192 MB.
// ---------------------------------------------------------------------------
__global__ void conv_kernel(const float* __restrict__ feat,
                            __half* __restrict__ feat_h, long n4) {
    long i = (long)blockIdx.x * blockDim.x + threadIdx.x;
    long stride = (long)gridDim.x * blockDim.x;
    for (; i < n4; i += stride) {
        float4 v = ((const float4*)feat)[i];
        H4 p;
        p.h[0] = __float2half_rn(v.x);
        p.h[1] = __float2half_rn(v.y);
        p.h[2] = __float2half_rn(v.z);
        p.h[3] = __float2half_rn(v.w);
        ((uint2*)feat_h)[i] = p.u;
    }
}

// ---------------------------------------------------------------------------
// seg_sum fp16: v4's exact structure/order, but rows are 64 halves = 128 B
// = ONE cache line per entry (f32 was 2). Halves both the random-line
// request count and L2-miss bytes on the proven 3.3 TB/s-limited path.
// One wave per domain, 16-lane groups, lane l16 owns channels 4*l16..+3,
// 4 entries per load phase, f32 accumulation in v4's order, butterfly fold.
// ---------------------------------------------------------------------------
__global__ void seg_sum_h_kernel(const __half* __restrict__ feat_h,
                                 const int* __restrict__ aidx,
                                 const int* __restrict__ starts,
                                 const int* __restrict__ ends,
                                 __half* __restrict__ T_h, int M) {
    int wid  = (int)(((size_t)blockIdx.x * blockDim.x + threadIdx.x) >> 6);
    if (wid >= M) return;
    int lane = threadIdx.x & 63;
    int g    = lane >> 4;          // entry-phase group 0..3
    int l16  = lane & 15;          // 4-half chunk within the 64-ch row
    int coff = l16 * 4;            // channel offset (8 B aligned in halves)

    int s = starts[wid];
    int e = ends[wid];

    float4 acc = make_float4(0.f, 0.f, 0.f, 0.f);
    if (s >= 0) {
        int last = e - 1;
        for (int base = s; base < e; base += 16) {
            int rem = e - base;            // uniform, >= 1
            int ti  = base + l16;
            int idxv = aidx[ti <= last ? ti : last];
            if (rem >= 16) {
#pragma unroll
                for (int p = 0; p < 4; ++p) {
                    int row = __shfl(idxv, p * 4 + g, 64);
                    H4 pk;
                    pk.u = *(const uint2*)(feat_h + (size_t)row * 64 + coff);
                    acc.x += __half2float(pk.h[0]);
                    acc.y += __half2float(pk.h[1]);
                    acc.z += __half2float(pk.h[2]);
                    acc.w += __half2float(pk.h[3]);
                }
            } else {
                int nph = (rem + 3) >> 2;  // uniform phase count
                for (int p = 0; p < nph; ++p) {
                    int t   = base + p * 4 + g;
                    int row = __shfl(idxv, p * 4 + g, 64);
                    H4 pk;
                    pk.u = *(const uint2*)(feat_h + (size_t)row * 64 + coff);
                    float w = (t <= last) ? 1.f : 0.f;
                    acc.x = fmaf(__half2float(pk.h[0]), w, acc.x);
                    acc.y = fmaf(__half2float(pk.h[1]), w, acc.y);
                    acc.z = fmaf(__half2float(pk.h[2]), w, acc.z);
                    acc.w = fmaf(__half2float(pk.h[3]), w, acc.w);
                }
            }
        }
        acc.x += __shfl_xor(acc.x, 16, 64);
        acc.y += __shfl_xor(acc.y, 16, 64);
        acc.z += __shfl_xor(acc.z, 16, 64);
        acc.w += __shfl_xor(acc.w, 16, 64);
        acc.x += __shfl_xor(acc.x, 32, 64);
        acc.y += __shfl_xor(acc.y, 32, 64);
        acc.z += __shfl_xor(acc.z, 32, 64);
        acc.w += __shfl_xor(acc.w, 32, 64);
    }
    if (g == 0) {
        H4 pk;
        pk.h[0] = __float2half_rn(acc.x);
        pk.h[1] = __float2half_rn(acc.y);
        pk.h[2] = __float2half_rn(acc.z);
        pk.h[3] = __float2half_rn(acc.w);
        *(uint2*)(T_h + (size_t)wid * 64 + coff) = pk.u;
    }
}

// ---------------------------------------------------------------------------
// Proj (fp16 T input): out = T @ W + b, 128x128 tile, 8x8 register blocking.
// HBM: 32 MB T_h read + 4 KB W + 125 MB out write. FMA floor 26 us.
// ---------------------------------------------------------------------------
#define TM 128

#define KSTEP(J, COMP)                                               \
    {                                                                \
        float4 wa = *(const float4*)&lds_w[kq * 4 + J][c0];          \
        float4 wb = *(const float4*)&lds_w[kq * 4 + J][c0 + 4];      \
        _Pragma("unroll")                                            \
        for (int r = 0; r < 8; ++r) {                                \
            float tv = tr[r].COMP;                                   \
            acc[r][0] = fmaf(tv, wa.x, acc[r][0]);                   \
            acc[r][1] = fmaf(tv, wa.y, acc[r][1]);                   \
            acc[r][2] = fmaf(tv, wa.z, acc[r][2]);                   \
            acc[r][3] = fmaf(tv, wa.w, acc[r][3]);                   \
            acc[r][4] = fmaf(tv, wb.x, acc[r][4]);                   \
            acc[r][5] = fmaf(tv, wb.y, acc[r][5]);                   \
            acc[r][6] = fmaf(tv, wb.z, acc[r][6]);                   \
            acc[r][7] = fmaf(tv, wb.w, acc[r][7]);                   \
        }                                                            \
    }

__global__ void __launch_bounds__(256)
proj_h_kernel(const __half* __restrict__ T_h,
              const float* __restrict__ W,
              const float* __restrict__ bias,
              float* __restrict__ out, int M) {
    __shared__ float lds_w[64][128];
    __shared__ float lds_t[64][TM + 4];

    int tid  = threadIdx.x;
    long row0 = (long)blockIdx.x * TM;

#pragma unroll
    for (int i = 0; i < 8; ++i) {
        int idx = tid + i * 256;
        int k   = idx >> 5;
        int ch  = idx & 31;
        float4 wv = ((const float4*)W)[idx];
        *(float4*)&lds_w[k][ch * 4] = wv;
    }
    // Stage T_h transposed: 128 rows x 16 uint2 chunks (4 halves), 8/thread.
#pragma unroll
    for (int i = 0; i < 8; ++i) {
        int idx = tid + i * 256;          // 0..2047
        int r   = idx >> 4;               // 0..127
        int ch  = idx & 15;               // 0..15
        long gr = row0 + r;
        if (gr > (long)M - 1) gr = (long)M - 1;
        H4 pk;
        pk.u = *(const uint2*)(T_h + gr * 64 + ch * 4);
        lds_t[ch * 4 + 0][r] = __half2float(pk.h[0]);
        lds_t[ch * 4 + 1][r] = __half2float(pk.h[1]);
        lds_t[ch * 4 + 2][r] = __half2float(pk.h[2]);
        lds_t[ch * 4 + 3][r] = __half2float(pk.h[3]);
    }
    __syncthreads();

    int c0 = (tid & 15) * 8;
    int r0 = (tid >> 4) * 8;

    float acc[8][8];
#pragma unroll
    for (int r = 0; r < 8; ++r)
#pragma unroll
        for (int c = 0; c < 8; ++c) acc[r][c] = 0.f;

#pragma unroll 2
    for (int kq = 0; kq < 16; ++kq) {
        float4 tr[8];
#pragma unroll
        for (int r = 0; r < 8; ++r) {
            float2 a = *(const float2*)&lds_t[kq * 4 + 0][r0 + r]; // dummy
            (void)a;
            break;
        }
        // read 8 T values per k from transposed tile
#pragma unroll
        for (int r = 0; r < 8; ++r)
            tr[r] = make_float4(lds_t[kq * 4 + 0][r0 + r],
                                lds_t[kq * 4 + 1][r0 + r],
                                lds_t[kq * 4 + 2][r0 + r],
                                lds_t[kq * 4 + 3][r0 + r]);
        KSTEP(0, x)
        KSTEP(1, y)
        KSTEP(2, z)
        KSTEP(3, w)
    }

    float4 bva = *(const float4*)&bias[c0];
    float4 bvb = *(const float4*)&bias[c0 + 4];
#pragma unroll
    for (int r = 0; r < 8; ++r) {
        long row = row0 + r0 + r;
        if (row < M) {
            float4 o0, o1;
            o0.x = acc[r][0] + bva.x;
            o0.y = acc[r][1] + bva.y;
            o0.z = acc[r][2] + bva.z;
            o0.w = acc[r][3] + bva.w;
            o1.x = acc[r][4] + bvb.x;
            o1.y = acc[r][5] + bvb.y;
            o1.z = acc[r][6] + bvb.z;
            o1.w = acc[r][7] + bvb.w;
            *(float4*)&out[row * 128 + c0]     = o0;
            *(float4*)&out[row * 128 + c0 + 4] = o1;
        }
    }
}

// ---------------------------------------------------------------------------
// Fallback exact-f32 path (round-3's verified kernels), used if ws_size
// can't hold feat_h + T_h + bounds.
// ---------------------------------------------------------------------------
__global__ void seg_sum_kernel(const float* __restrict__ feat,
                               const int* __restrict__ aidx,
                               const int* __restrict__ starts,
                               const int* __restrict__ ends,
                               float* __restrict__ T, int M) {
    int wid  = (int)(((size_t)blockIdx.x * blockDim.x + threadIdx.x) >> 6);
    if (wid >= M) return;
    int lane = threadIdx.x & 63;
    int g    = lane >> 4;
    int l16  = lane & 15;
    int coff = l16 * 4;

    int s = starts[wid];
    int e = ends[wid];

    float4 acc = make_float4(0.f, 0.f, 0.f, 0.f);
    if (s >= 0) {
        int last = e - 1;
        for (int base = s; base < e; base += 16) {
            int rem = e - base;
            int ti  = base + l16;
            int idxv = aidx[ti <= last ? ti : last];
            if (rem >= 16) {
#pragma unroll
                for (int p = 0; p < 4; ++p) {
                    int row = __shfl(idxv, p * 4 + g, 64);
                    const float4 v =
                        *(const float4*)(feat + (size_t)row * 64 + coff);
                    acc.x += v.x; acc.y += v.y; acc.z += v.z; acc.w += v.w;
                }
            } else {
                int nph = (rem + 3) >> 2;
                for (int p = 0; p < nph; ++p) {
                    int t   = base + p * 4 + g;
                    int row = __shfl(idxv, p * 4 + g, 64);
                    const float4 v =
                        *(const float4*)(feat + (size_t)row * 64 + coff);
                    float w = (t <= last) ? 1.f : 0.f;
                    acc.x = fmaf(v.x, w, acc.x);
                    acc.y = fmaf(v.y, w, acc.y);
                    acc.z = fmaf(v.z, w, acc.z);
                    acc.w = fmaf(v.w, w, acc.w);
                }
            }
        }
        acc.x += __shfl_xor(acc.x, 16, 64);
        acc.y += __shfl_xor(acc.y, 16, 64);
        acc.z += __shfl_xor(acc.z, 16, 64);
        acc.w += __shfl_xor(acc.w, 16, 64);
        acc.x += __shfl_xor(acc.x, 32, 64);
        acc.y += __shfl_xor(acc.y, 32, 64);
        acc.z += __shfl_xor(acc.z, 32, 64);
        acc.w += __shfl_xor(acc.w, 32, 64);
    }
    if (g == 0)
        *(float4*)(T + (size_t)wid * 64 + coff) = acc;
}

__global__ void __launch_bounds__(256)
proj_kernel(const float* __restrict__ T,
            const float* __restrict__ W,
            const float* __restrict__ bias,
            float* __restrict__ out, int M) {
    __shared__ float lds_w[64][128];
    __shared__ float lds_t[64][TM + 4];

    int tid  = threadIdx.x;
    long row0 = (long)blockIdx.x * TM;

#pragma unroll
    for (int i = 0; i < 8; ++i) {
        int idx = tid + i * 256;
        int k   = idx >> 5;
        int ch  = idx & 31;
        float4 wv = ((const float4*)W)[idx];
        *(float4*)&lds_w[k][ch * 4] = wv;
    }
#pragma unroll
    for (int i = 0; i < 8; ++i) {
        int idx = tid + i * 256;
        int r   = idx >> 4;
        int ch  = idx & 15;
        long gr = row0 + r;
        if (gr > (long)M - 1) gr = (long)M - 1;
        float4 tv = ((const float4*)(T + gr * 64))[ch];
        lds_t[ch * 4 + 0][r] = tv.x;
        lds_t[ch * 4 + 1][r] = tv.y;
        lds_t[ch * 4 + 2][r] = tv.z;
        lds_t[ch * 4 + 3][r] = tv.w;
    }
    __syncthreads();

    int c0 = (tid & 15) * 8;
    int r0 = (tid >> 4) * 8;

    float acc[8][8];
#pragma unroll
    for (int r = 0; r < 8; ++r)
#pragma unroll
        for (int c = 0; c < 8; ++c) acc[r][c] = 0.f;

#pragma unroll 2
    for (int kq = 0; kq < 16; ++kq) {
        float4 tr[8];
#pragma unroll
        for (int r = 0; r < 8; ++r)
            tr[r] = *(const float4*)&lds_t[r0 + r][kq * 4];
        // NOTE: fallback keeps round-3 row-major tile reads
        KSTEP(0, x)
        KSTEP(1, y)
        KSTEP(2, z)
        KSTEP(3, w)
    }

    float4 bva = *(const float4*)&bias[c0];
    float4 bvb = *(const float4*)&bias[c0 + 4];
#pragma unroll
    for (int r = 0; r < 8; ++r) {
        long row = row0 + r0 + r;
        if (row < M) {
            float4 o0, o1;
            o0.x = acc[r][0] + bva.x;
            o0.y = acc[r][1] + bva.y;
            o0.z = acc[r][2] + bva.z;
            o0.w = acc[r][3] + bva.w;
            o1.x = acc[r][4] + bvb.x;
            o1.y = acc[r][5] + bvb.y;
            o1.z = acc[r][6] + bvb.z;
            o1.w = acc[r][7] + bvb.w;
            *(float4*)&out[row * 128 + c0]     = o0;
            *(float4*)&out[row * 128 + c0 + 4] = o1;
        }
    }
}

extern "C" void kernel_launch(void* const* d_in, const int* in_sizes, int n_in,
                              void* d_out, int out_size, void* d_ws, size_t ws_size,
                              hipStream_t stream) {
    const float* feat = (const float*)d_in[0];   // [N_ATOMS, 64] f32
    const int*   aidx = (const int*)d_in[1];     // [E] int
    const int*   dids = (const int*)d_in[2];     // [E] int (sorted)
    const float* W    = (const float*)d_in[4];   // [64, 128] f32
    const float* bias = (const float*)d_in[5];   // [128] f32
    float*       out  = (float*)d_out;           // [M, 128] f32

    int E = in_sizes[1];
    int M = out_size / 128;
    long nfeat = in_sizes[0];                    // N_ATOMS * 64 elements

    size_t fh_bytes = (size_t)nfeat * 2;               // fp16 features
    size_t th_bytes = (size_t)M * 64 * 2;              // fp16 T
    size_t bbytes   = 2 * (size_t)M * sizeof(int);     // bounds

    int waves_blocks = (int)(((size_t)M * 64 + 255) / 256);

    if (ws_size >= fh_bytes + th_bytes + bbytes) {
        // -------- fp16 path: 1-line gather rows --------
        __half* feat_h = (__half*)d_ws;
        __half* T_h    = (__half*)((char*)d_ws + fh_bytes);
        int* starts    = (int*)((char*)d_ws + fh_bytes + th_bytes);
        int* ends      = starts + M;

        hipMemsetAsync(starts, 0xFF, bbytes, stream);
        conv_kernel<<<2048, 256, 0, stream>>>(feat, feat_h, nfeat / 4);
        bounds_kernel<<<(E + 255) / 256, 256, 0, stream>>>(dids, starts, ends, E);
        seg_sum_h_kernel<<<waves_blocks, 256, 0, stream>>>(feat_h, aidx,
                                                           starts, ends, T_h, M);
        proj_h_kernel<<<(M + TM - 1) / TM, 256, 0, stream>>>(T_h, W, bias, out, M);
    } else {
        // -------- exact f32 fallback (round-3 verified) --------
        float* T = (float*)d_ws;
        size_t tbytes = (size_t)M * 64 * sizeof(float);
        int* starts;
        if (ws_size >= tbytes + bbytes) {
            starts = (int*)((char*)d_ws + tbytes);
        } else {
            starts = (int*)((char*)d_out + (size_t)out_size * sizeof(float) - bbytes);
        }
        int* ends = starts + M;

        hipMemsetAsync(starts, 0xFF, bbytes, stream);
        bounds_kernel<<<(E + 255) / 256, 256, 0, stream>>>(dids, starts, ends, E);
        seg_sum_kernel<<<waves_blocks, 256, 0, stream>>>(feat, aidx, starts, ends, T, M);
        proj_kernel<<<(M + TM - 1) / TM, 256, 0, stream>>>(T, W, bias, out, M);
    }
}

// Round 7
// 410.583 us; speedup vs baseline: 1.4147x; 1.0240x over previous
//
#include <hip/hip_runtime.h>
#include <hip/hip_fp16.h>

union H4 { uint2 u; __half h[4]; };
union H8 { uint4 u; __half h[8]; };

// ---------------------------------------------------------------------------
// Kernel A: segment boundaries in SORTED domain_ids.
// starts[d]=-1 (memset 0xFF) means empty domain.
// ---------------------------------------------------------------------------
__global__ void bounds_kernel(const int* __restrict__ dids,
                              int* __restrict__ starts,
                              int* __restrict__ ends, int E) {
    int e = blockIdx.x * blockDim.x + threadIdx.x;
    if (e >= E) return;
    int d = dids[e];
    if (e == 0) {
        starts[d] = 0;
    } else {
        int dp = dids[e - 1];
        if (d != dp) {
            starts[d] = e;
            ends[dp]  = e;
        }
    }
    if (e == E - 1) ends[d] = E;
}

// ---------------------------------------------------------------------------
// Conv: features f32 -> fp16 (once per launch). Streaming, ~192 MB.
// ---------------------------------------------------------------------------
__global__ void conv_kernel(const float* __restrict__ feat,
                            __half* __restrict__ feat_h, long n4) {
    long i = (long)blockIdx.x * blockDim.x + threadIdx.x;
    long stride = (long)gridDim.x * blockDim.x;
    for (; i < n4; i += stride) {
        float4 v = ((const float4*)feat)[i];
        H4 p;
        p.h[0] = __float2half_rn(v.x);
        p.h[1] = __float2half_rn(v.y);
        p.h[2] = __float2half_rn(v.z);
        p.h[3] = __float2half_rn(v.w);
        ((uint2*)feat_h)[i] = p.u;
    }
}

// ---------------------------------------------------------------------------
// seg_sum fp16 v2: one wave per domain; 8-lane groups each read a FULL
// 128-B feature row as uint4 (16 B/lane). 8 entries per wave-load phase
// (v1 was 4) -> 500K wave-loads total (was 1M), same L2-miss line count.
// Attacks the measured ~41 cyc/wave-load fixed cost (two-point fit across
// f32/fp16 rounds); fabric line term (~27 ps/line) unchanged.
// Per 16-entry batch: 1 index vector-load (lanes 0-15 pattern, 4x dup),
// 2 gather phases via __shfl index distribution, f32 accumulation,
// 3-step butterfly fold (xor 8,16,32), lanes 0-7 store the 128-B T_h row.
// ---------------------------------------------------------------------------
__global__ void seg_sum_h_kernel(const __half* __restrict__ feat_h,
                                 const int* __restrict__ aidx,
                                 const int* __restrict__ starts,
                                 const int* __restrict__ ends,
                                 __half* __restrict__ T_h, int M) {
    int wid  = (int)(((size_t)blockIdx.x * blockDim.x + threadIdx.x) >> 6);
    if (wid >= M) return;
    int lane = threadIdx.x & 63;
    int g8   = lane >> 3;          // entry-phase group 0..7
    int l8   = lane & 7;           // uint4 chunk within the 64-ch row
    int coff = l8 * 8;             // channel offset (halves)

    int s = starts[wid];
    int e = ends[wid];

    float acc[8];
#pragma unroll
    for (int j = 0; j < 8; ++j) acc[j] = 0.f;

    if (s >= 0) {
        int last = e - 1;
        for (int base = s; base < e; base += 16) {
            int rem = e - base;            // uniform, >= 1
            int ti  = base + (lane & 15);
            // 16 distinct dwords, 4x lane-duplicated -> one coalesced request
            int idxv = aidx[ti <= last ? ti : last];
            if (rem >= 16) {
                int r0 = __shfl(idxv, g8, 64);
                int r1 = __shfl(idxv, 8 + g8, 64);
                H8 p0, p1;
                p0.u = *(const uint4*)(feat_h + (size_t)r0 * 64 + coff);
                p1.u = *(const uint4*)(feat_h + (size_t)r1 * 64 + coff);
#pragma unroll
                for (int j = 0; j < 8; ++j) acc[j] += __half2float(p0.h[j]);
#pragma unroll
                for (int j = 0; j < 8; ++j) acc[j] += __half2float(p1.h[j]);
            } else {
                int nph = (rem + 7) >> 3;  // uniform phase count (1 or 2)
                for (int p = 0; p < nph; ++p) {
                    int t   = base + p * 8 + g8;
                    int row = __shfl(idxv, p * 8 + g8, 64);
                    H8 pk;
                    pk.u = *(const uint4*)(feat_h + (size_t)row * 64 + coff);
                    float w = (t <= last) ? 1.f : 0.f;
#pragma unroll
                    for (int j = 0; j < 8; ++j)
                        acc[j] = fmaf(__half2float(pk.h[j]), w, acc[j]);
                }
            }
        }
        // fold the 8 group partials: butterfly over lane bits 3,4,5
#pragma unroll
        for (int j = 0; j < 8; ++j) {
            acc[j] += __shfl_xor(acc[j], 8, 64);
            acc[j] += __shfl_xor(acc[j], 16, 64);
            acc[j] += __shfl_xor(acc[j], 32, 64);
        }
    }
    if (g8 == 0) {
        H8 o;
#pragma unroll
        for (int j = 0; j < 8; ++j) o.h[j] = __float2half_rn(acc[j]);
        *(uint4*)(T_h + (size_t)wid * 64 + coff) = o.u;
    }
}

// ---------------------------------------------------------------------------
// Proj v2 (fp16 T input): round-3-verified v5 structure. 128x128 tile,
// 8x8 register blocking, [k][row] LDS tile, ds_read_b128 row reads
// (v7's 32x scalar stride-132 b32 reads were the regression).
// HBM: 32 MB T_h read + 125 MB out write. FMA floor 26 us.
// ---------------------------------------------------------------------------
#define TM 128
__global__ void __launch_bounds__(256)
proj_h_kernel(const __half* __restrict__ T_h,
              const float* __restrict__ W,
              const float* __restrict__ bias,
              float* __restrict__ out, int M) {
    __shared__ float lds_w[64][128];
    __shared__ float lds_t[64][TM + 4];   // [k][row], stride 132 floats

    int tid  = threadIdx.x;
    long row0 = (long)blockIdx.x * TM;

#pragma unroll
    for (int i = 0; i < 8; ++i) {
        int idx = tid + i * 256;
        int k   = idx >> 5;
        int ch  = idx & 31;
        float4 wv = ((const float4*)W)[idx];
        *(float4*)&lds_w[k][ch * 4] = wv;
    }
    // Stage T_h transposed: 128 rows x 16 uint2 chunks (4 halves), 8/thread.
#pragma unroll
    for (int i = 0; i < 8; ++i) {
        int idx = tid + i * 256;          // 0..2047
        int r   = idx >> 4;               // 0..127
        int ch  = idx & 15;               // 0..15
        long gr = row0 + r;
        if (gr > (long)M - 1) gr = (long)M - 1;
        H4 pk;
        pk.u = *(const uint2*)(T_h + gr * 64 + ch * 4);
        lds_t[ch * 4 + 0][r] = __half2float(pk.h[0]);
        lds_t[ch * 4 + 1][r] = __half2float(pk.h[1]);
        lds_t[ch * 4 + 2][r] = __half2float(pk.h[2]);
        lds_t[ch * 4 + 3][r] = __half2float(pk.h[3]);
    }
    __syncthreads();

    int c0 = (tid & 15) * 8;
    int r0 = (tid >> 4) * 8;

    float acc[8][8];
#pragma unroll
    for (int r = 0; r < 8; ++r)
#pragma unroll
        for (int c = 0; c < 8; ++c) acc[r][c] = 0.f;

#pragma unroll 4
    for (int k = 0; k < 64; ++k) {
        float4 ta = *(const float4*)&lds_t[k][r0];
        float4 tb = *(const float4*)&lds_t[k][r0 + 4];
        float4 wa = *(const float4*)&lds_w[k][c0];
        float4 wb = *(const float4*)&lds_w[k][c0 + 4];
        float t[8] = {ta.x, ta.y, ta.z, ta.w, tb.x, tb.y, tb.z, tb.w};
        float w[8] = {wa.x, wa.y, wa.z, wa.w, wb.x, wb.y, wb.z, wb.w};
#pragma unroll
        for (int r = 0; r < 8; ++r)
#pragma unroll
            for (int c = 0; c < 8; ++c)
                acc[r][c] = fmaf(t[r], w[c], acc[r][c]);
    }

    float4 bva = *(const float4*)&bias[c0];
    float4 bvb = *(const float4*)&bias[c0 + 4];
#pragma unroll
    for (int r = 0; r < 8; ++r) {
        long row = row0 + r0 + r;
        if (row < M) {
            float4 o0, o1;
            o0.x = acc[r][0] + bva.x;
            o0.y = acc[r][1] + bva.y;
            o0.z = acc[r][2] + bva.z;
            o0.w = acc[r][3] + bva.w;
            o1.x = acc[r][4] + bvb.x;
            o1.y = acc[r][5] + bvb.y;
            o1.z = acc[r][6] + bvb.z;
            o1.w = acc[r][7] + bvb.w;
            *(float4*)&out[row * 128 + c0]     = o0;
            *(float4*)&out[row * 128 + c0 + 4] = o1;
        }
    }
}

// ---------------------------------------------------------------------------
// Fallback exact-f32 path (round-3 verified structure), used only if
// ws_size can't hold feat_h + T_h + bounds.
// ---------------------------------------------------------------------------
__global__ void seg_sum_kernel(const float* __restrict__ feat,
                               const int* __restrict__ aidx,
                               const int* __restrict__ starts,
                               const int* __restrict__ ends,
                               float* __restrict__ T, int M) {
    int wid  = (int)(((size_t)blockIdx.x * blockDim.x + threadIdx.x) >> 6);
    if (wid >= M) return;
    int lane = threadIdx.x & 63;
    int g    = lane >> 4;
    int l16  = lane & 15;
    int coff = l16 * 4;

    int s = starts[wid];
    int e = ends[wid];

    float4 acc = make_float4(0.f, 0.f, 0.f, 0.f);
    if (s >= 0) {
        int last = e - 1;
        for (int base = s; base < e; base += 16) {
            int rem = e - base;
            int ti  = base + l16;
            int idxv = aidx[ti <= last ? ti : last];
            if (rem >= 16) {
#pragma unroll
                for (int p = 0; p < 4; ++p) {
                    int row = __shfl(idxv, p * 4 + g, 64);
                    const float4 v =
                        *(const float4*)(feat + (size_t)row * 64 + coff);
                    acc.x += v.x; acc.y += v.y; acc.z += v.z; acc.w += v.w;
                }
            } else {
                int nph = (rem + 3) >> 2;
                for (int p = 0; p < nph; ++p) {
                    int t   = base + p * 4 + g;
                    int row = __shfl(idxv, p * 4 + g, 64);
                    const float4 v =
                        *(const float4*)(feat + (size_t)row * 64 + coff);
                    float w = (t <= last) ? 1.f : 0.f;
                    acc.x = fmaf(v.x, w, acc.x);
                    acc.y = fmaf(v.y, w, acc.y);
                    acc.z = fmaf(v.z, w, acc.z);
                    acc.w = fmaf(v.w, w, acc.w);
                }
            }
        }
        acc.x += __shfl_xor(acc.x, 16, 64);
        acc.y += __shfl_xor(acc.y, 16, 64);
        acc.z += __shfl_xor(acc.z, 16, 64);
        acc.w += __shfl_xor(acc.w, 16, 64);
        acc.x += __shfl_xor(acc.x, 32, 64);
        acc.y += __shfl_xor(acc.y, 32, 64);
        acc.z += __shfl_xor(acc.z, 32, 64);
        acc.w += __shfl_xor(acc.w, 32, 64);
    }
    if (g == 0)
        *(float4*)(T + (size_t)wid * 64 + coff) = acc;
}

__global__ void __launch_bounds__(256)
proj_kernel(const float* __restrict__ T,
            const float* __restrict__ W,
            const float* __restrict__ bias,
            float* __restrict__ out, int M) {
    __shared__ float lds_w[64][128];
    __shared__ float lds_t[64][TM + 4];   // [k][row]

    int tid  = threadIdx.x;
    long row0 = (long)blockIdx.x * TM;

#pragma unroll
    for (int i = 0; i < 8; ++i) {
        int idx = tid + i * 256;
        int k   = idx >> 5;
        int ch  = idx & 31;
        float4 wv = ((const float4*)W)[idx];
        *(float4*)&lds_w[k][ch * 4] = wv;
    }
#pragma unroll
    for (int i = 0; i < 8; ++i) {
        int idx = tid + i * 256;
        int r   = idx >> 4;
        int ch  = idx & 15;
        long gr = row0 + r;
        if (gr > (long)M - 1) gr = (long)M - 1;
        float4 tv = ((const float4*)(T + gr * 64))[ch];
        lds_t[ch * 4 + 0][r] = tv.x;
        lds_t[ch * 4 + 1][r] = tv.y;
        lds_t[ch * 4 + 2][r] = tv.z;
        lds_t[ch * 4 + 3][r] = tv.w;
    }
    __syncthreads();

    int c0 = (tid & 15) * 8;
    int r0 = (tid >> 4) * 8;

    float acc[8][8];
#pragma unroll
    for (int r = 0; r < 8; ++r)
#pragma unroll
        for (int c = 0; c < 8; ++c) acc[r][c] = 0.f;

#pragma unroll 4
    for (int k = 0; k < 64; ++k) {
        float4 ta = *(const float4*)&lds_t[k][r0];
        float4 tb = *(const float4*)&lds_t[k][r0 + 4];
        float4 wa = *(const float4*)&lds_w[k][c0];
        float4 wb = *(const float4*)&lds_w[k][c0 + 4];
        float t[8] = {ta.x, ta.y, ta.z, ta.w, tb.x, tb.y, tb.z, tb.w};
        float w[8] = {wa.x, wa.y, wa.z, wa.w, wb.x, wb.y, wb.z, wb.w};
#pragma unroll
        for (int r = 0; r < 8; ++r)
#pragma unroll
            for (int c = 0; c < 8; ++c)
                acc[r][c] = fmaf(t[r], w[c], acc[r][c]);
    }

    float4 bva = *(const float4*)&bias[c0];
    float4 bvb = *(const float4*)&bias[c0 + 4];
#pragma unroll
    for (int r = 0; r < 8; ++r) {
        long row = row0 + r0 + r;
        if (row < M) {
            float4 o0, o1;
            o0.x = acc[r][0] + bva.x;
            o0.y = acc[r][1] + bva.y;
            o0.z = acc[r][2] + bva.z;
            o0.w = acc[r][3] + bva.w;
            o1.x = acc[r][4] + bvb.x;
            o1.y = acc[r][5] + bvb.y;
            o1.z = acc[r][6] + bvb.z;
            o1.w = acc[r][7] + bvb.w;
            *(float4*)&out[row * 128 + c0]     = o0;
            *(float4*)&out[row * 128 + c0 + 4] = o1;
        }
    }
}

extern "C" void kernel_launch(void* const* d_in, const int* in_sizes, int n_in,
                              void* d_out, int out_size, void* d_ws, size_t ws_size,
                              hipStream_t stream) {
    const float* feat = (const float*)d_in[0];   // [N_ATOMS, 64] f32
    const int*   aidx = (const int*)d_in[1];     // [E] int
    const int*   dids = (const int*)d_in[2];     // [E] int (sorted)
    const float* W    = (const float*)d_in[4];   // [64, 128] f32
    const float* bias = (const float*)d_in[5];   // [128] f32
    float*       out  = (float*)d_out;           // [M, 128] f32

    int E = in_sizes[1];
    int M = out_size / 128;
    long nfeat = in_sizes[0];                    // N_ATOMS * 64 elements

    size_t fh_bytes = (size_t)nfeat * 2;               // fp16 features
    size_t th_bytes = (size_t)M * 64 * 2;              // fp16 T
    size_t bbytes   = 2 * (size_t)M * sizeof(int);     // bounds

    int waves_blocks = (int)(((size_t)M * 64 + 255) / 256);

    if (ws_size >= fh_bytes + th_bytes + bbytes) {
        // -------- fp16 path: 1-line gather rows --------
        __half* feat_h = (__half*)d_ws;
        __half* T_h    = (__half*)((char*)d_ws + fh_bytes);
        int* starts    = (int*)((char*)d_ws + fh_bytes + th_bytes);
        int* ends      = starts + M;

        hipMemsetAsync(starts, 0xFF, bbytes, stream);
        conv_kernel<<<2048, 256, 0, stream>>>(feat, feat_h, nfeat / 4);
        bounds_kernel<<<(E + 255) / 256, 256, 0, stream>>>(dids, starts, ends, E);
        seg_sum_h_kernel<<<waves_blocks, 256, 0, stream>>>(feat_h, aidx,
                                                           starts, ends, T_h, M);
        proj_h_kernel<<<(M + TM - 1) / TM, 256, 0, stream>>>(T_h, W, bias, out, M);
    } else {
        // -------- exact f32 fallback (round-3 verified) --------
        float* T = (float*)d_ws;
        size_t tbytes = (size_t)M * 64 * sizeof(float);
        int* starts;
        if (ws_size >= tbytes + bbytes) {
            starts = (int*)((char*)d_ws + tbytes);
        } else {
            starts = (int*)((char*)d_out + (size_t)out_size * sizeof(float) - bbytes);
        }
        int* ends = starts + M;

        hipMemsetAsync(starts, 0xFF, bbytes, stream);
        bounds_kernel<<<(E + 255) / 256, 256, 0, stream>>>(dids, starts, ends, E);
        seg_sum_kernel<<<waves_blocks, 256, 0, stream>>>(feat, aidx, starts, ends, T, M);
        proj_kernel<<<(M + TM - 1) / TM, 256, 0, stream>>>(T, W, bias, out, M);
    }
}

// Round 8
// 398.319 us; speedup vs baseline: 1.4582x; 1.0308x over previous
//
#include <hip/hip_runtime.h>
#include <hip/hip_fp16.h>

union H4 { uint2 u; __half h[4]; };
union H8 { uint4 u; __half h[8]; };

// ---------------------------------------------------------------------------
// Fused conv + bounds: grid-stride over both ranges.
//  - conv: features f32 -> fp16 (~192 MB streaming)
//  - bounds: segment boundaries in SORTED domain_ids (16 MB read, hides
//    under the conv stream). starts[d]=-1 (memset 0xFF) = empty domain.
// ---------------------------------------------------------------------------
__global__ void conv_bounds_kernel(const float* __restrict__ feat,
                                   __half* __restrict__ feat_h, long n4,
                                   const int* __restrict__ dids,
                                   int* __restrict__ starts,
                                   int* __restrict__ ends, int E) {
    long gid = (long)blockIdx.x * blockDim.x + threadIdx.x;
    long gsz = (long)gridDim.x * blockDim.x;
    for (long i = gid; i < n4; i += gsz) {
        float4 v = ((const float4*)feat)[i];
        H4 p;
        p.h[0] = __float2half_rn(v.x);
        p.h[1] = __float2half_rn(v.y);
        p.h[2] = __float2half_rn(v.z);
        p.h[3] = __float2half_rn(v.w);
        ((uint2*)feat_h)[i] = p.u;
    }
    for (long e = gid; e < E; e += gsz) {
        int d = dids[e];
        if (e == 0) {
            starts[d] = 0;
        } else {
            int dp = dids[e - 1];
            if (d != dp) {
                starts[d] = (int)e;
                ends[dp]  = (int)e;
            }
        }
        if (e == E - 1) ends[d] = (int)e + 1;
    }
}

// Standalone bounds for the f32 fallback path.
__global__ void bounds_kernel(const int* __restrict__ dids,
                              int* __restrict__ starts,
                              int* __restrict__ ends, int E) {
    int e = blockIdx.x * blockDim.x + threadIdx.x;
    if (e >= E) return;
    int d = dids[e];
    if (e == 0) {
        starts[d] = 0;
    } else {
        int dp = dids[e - 1];
        if (d != dp) {
            starts[d] = e;
            ends[dp]  = e;
        }
    }
    if (e == E - 1) ends[d] = E;
}

// ---------------------------------------------------------------------------
// seg_sum fp16 (UNCHANGED — control; measured 116 us, FETCH 255 MB,
// at the random-128B-line fabric ceiling ~2.2 TB/s fetch-side).
// One wave per domain; 8-lane groups read full 128-B rows as uint4,
// 8 entries per wave-load phase, f32 accumulation, 3-step butterfly fold.
// ---------------------------------------------------------------------------
__global__ void seg_sum_h_kernel(const __half* __restrict__ feat_h,
                                 const int* __restrict__ aidx,
                                 const int* __restrict__ starts,
                                 const int* __restrict__ ends,
                                 __half* __restrict__ T_h, int M) {
    int wid  = (int)(((size_t)blockIdx.x * blockDim.x + threadIdx.x) >> 6);
    if (wid >= M) return;
    int lane = threadIdx.x & 63;
    int g8   = lane >> 3;          // entry-phase group 0..7
    int l8   = lane & 7;           // uint4 chunk within the 64-ch row
    int coff = l8 * 8;             // channel offset (halves)

    int s = starts[wid];
    int e = ends[wid];

    float acc[8];
#pragma unroll
    for (int j = 0; j < 8; ++j) acc[j] = 0.f;

    if (s >= 0) {
        int last = e - 1;
        for (int base = s; base < e; base += 16) {
            int rem = e - base;            // uniform, >= 1
            int ti  = base + (lane & 15);
            int idxv = aidx[ti <= last ? ti : last];
            if (rem >= 16) {
                int r0 = __shfl(idxv, g8, 64);
                int r1 = __shfl(idxv, 8 + g8, 64);
                H8 p0, p1;
                p0.u = *(const uint4*)(feat_h + (size_t)r0 * 64 + coff);
                p1.u = *(const uint4*)(feat_h + (size_t)r1 * 64 + coff);
#pragma unroll
                for (int j = 0; j < 8; ++j) acc[j] += __half2float(p0.h[j]);
#pragma unroll
                for (int j = 0; j < 8; ++j) acc[j] += __half2float(p1.h[j]);
            } else {
                int nph = (rem + 7) >> 3;  // uniform phase count (1 or 2)
                for (int p = 0; p < nph; ++p) {
                    int t   = base + p * 8 + g8;
                    int row = __shfl(idxv, p * 8 + g8, 64);
                    H8 pk;
                    pk.u = *(const uint4*)(feat_h + (size_t)row * 64 + coff);
                    float w = (t <= last) ? 1.f : 0.f;
#pragma unroll
                    for (int j = 0; j < 8; ++j)
                        acc[j] = fmaf(__half2float(pk.h[j]), w, acc[j]);
                }
            }
        }
#pragma unroll
        for (int j = 0; j < 8; ++j) {
            acc[j] += __shfl_xor(acc[j], 8, 64);
            acc[j] += __shfl_xor(acc[j], 16, 64);
            acc[j] += __shfl_xor(acc[j], 32, 64);
        }
    }
    if (g8 == 0) {
        H8 o;
#pragma unroll
        for (int j = 0; j < 8; ++j) o.h[j] = __float2half_rn(acc[j]);
        *(uint4*)(T_h + (size_t)wid * 64 + coff) = o.u;
    }
}

// ---------------------------------------------------------------------------
// Proj v3 (fp16 T in LDS): 128x128 tile, 8x8 register blocking.
// T tile stays fp16 in LDS ([64][136] halves, 17 KB) — bit-identical to
// converting at stage time (T_h is already fp16). Per thread per k:
// 1x b128 T (8 halves) + 2x b128 W = 48 B per 64 FMA (was 64 B), and
// LDS total 49 KB -> 3 blocks/CU (was 66 KB -> 2): staging/store phases
// hide behind the third block. FMA floor 26 us; LDS ~29 us.
// T-stage lanes run along rows (2 B x 64 contiguous lanes = 2 lanes/bank,
// free); global side reads 8 B/lane stride-128 (L2-hot, 16 KB/block).
// ---------------------------------------------------------------------------
#define TM 128
__global__ void __launch_bounds__(256)
proj_h_kernel(const __half* __restrict__ T_h,
              const float* __restrict__ W,
              const float* __restrict__ bias,
              float* __restrict__ out, int M) {
    __shared__ float lds_w[64][128];
    __shared__ __align__(16) __half lds_th[64][TM + 8];  // stride 272 B

    int tid  = threadIdx.x;
    long row0 = (long)blockIdx.x * TM;

#pragma unroll
    for (int i = 0; i < 8; ++i) {
        int idx = tid + i * 256;
        int k   = idx >> 5;
        int ch  = idx & 31;
        float4 wv = ((const float4*)W)[idx];
        *(float4*)&lds_w[k][ch * 4] = wv;
    }
    // Stage T_h: idx over 0..2047; r = idx&127 (lane-major), c8 = idx>>7.
#pragma unroll
    for (int i = 0; i < 8; ++i) {
        int idx = tid + i * 256;
        int r   = idx & (TM - 1);
        int c8  = idx >> 7;               // 0..15: chunk of 4 halves
        long gr = row0 + r;
        if (gr > (long)M - 1) gr = (long)M - 1;
        H4 pk;
        pk.u = *(const uint2*)(T_h + gr * 64 + c8 * 4);
        lds_th[c8 * 4 + 0][r] = pk.h[0];
        lds_th[c8 * 4 + 1][r] = pk.h[1];
        lds_th[c8 * 4 + 2][r] = pk.h[2];
        lds_th[c8 * 4 + 3][r] = pk.h[3];
    }
    __syncthreads();

    int c0 = (tid & 15) * 8;
    int r0 = (tid >> 4) * 8;

    float acc[8][8];
#pragma unroll
    for (int r = 0; r < 8; ++r)
#pragma unroll
        for (int c = 0; c < 8; ++c) acc[r][c] = 0.f;

#pragma unroll 4
    for (int k = 0; k < 64; ++k) {
        H8 th;
        th.u = *(const uint4*)&lds_th[k][r0];
        float4 wa = *(const float4*)&lds_w[k][c0];
        float4 wb = *(const float4*)&lds_w[k][c0 + 4];
        float t[8];
#pragma unroll
        for (int r = 0; r < 8; ++r) t[r] = __half2float(th.h[r]);
        float w[8] = {wa.x, wa.y, wa.z, wa.w, wb.x, wb.y, wb.z, wb.w};
#pragma unroll
        for (int r = 0; r < 8; ++r)
#pragma unroll
            for (int c = 0; c < 8; ++c)
                acc[r][c] = fmaf(t[r], w[c], acc[r][c]);
    }

    float4 bva = *(const float4*)&bias[c0];
    float4 bvb = *(const float4*)&bias[c0 + 4];
#pragma unroll
    for (int r = 0; r < 8; ++r) {
        long row = row0 + r0 + r;
        if (row < M) {
            float4 o0, o1;
            o0.x = acc[r][0] + bva.x;
            o0.y = acc[r][1] + bva.y;
            o0.z = acc[r][2] + bva.z;
            o0.w = acc[r][3] + bva.w;
            o1.x = acc[r][4] + bvb.x;
            o1.y = acc[r][5] + bvb.y;
            o1.z = acc[r][6] + bvb.z;
            o1.w = acc[r][7] + bvb.w;
            *(float4*)&out[row * 128 + c0]     = o0;
            *(float4*)&out[row * 128 + c0 + 4] = o1;
        }
    }
}

// ---------------------------------------------------------------------------
// Fallback exact-f32 path (round-3 verified structure), used only if
// ws_size can't hold feat_h + T_h + bounds.
// ---------------------------------------------------------------------------
__global__ void seg_sum_kernel(const float* __restrict__ feat,
                               const int* __restrict__ aidx,
                               const int* __restrict__ starts,
                               const int* __restrict__ ends,
                               float* __restrict__ T, int M) {
    int wid  = (int)(((size_t)blockIdx.x * blockDim.x + threadIdx.x) >> 6);
    if (wid >= M) return;
    int lane = threadIdx.x & 63;
    int g    = lane >> 4;
    int l16  = lane & 15;
    int coff = l16 * 4;

    int s = starts[wid];
    int e = ends[wid];

    float4 acc = make_float4(0.f, 0.f, 0.f, 0.f);
    if (s >= 0) {
        int last = e - 1;
        for (int base = s; base < e; base += 16) {
            int rem = e - base;
            int ti  = base + l16;
            int idxv = aidx[ti <= last ? ti : last];
            if (rem >= 16) {
#pragma unroll
                for (int p = 0; p < 4; ++p) {
                    int row = __shfl(idxv, p * 4 + g, 64);
                    const float4 v =
                        *(const float4*)(feat + (size_t)row * 64 + coff);
                    acc.x += v.x; acc.y += v.y; acc.z += v.z; acc.w += v.w;
                }
            } else {
                int nph = (rem + 3) >> 2;
                for (int p = 0; p < nph; ++p) {
                    int t   = base + p * 4 + g;
                    int row = __shfl(idxv, p * 4 + g, 64);
                    const float4 v =
                        *(const float4*)(feat + (size_t)row * 64 + coff);
                    float w = (t <= last) ? 1.f : 0.f;
                    acc.x = fmaf(v.x, w, acc.x);
                    acc.y = fmaf(v.y, w, acc.y);
                    acc.z = fmaf(v.z, w, acc.z);
                    acc.w = fmaf(v.w, w, acc.w);
                }
            }
        }
        acc.x += __shfl_xor(acc.x, 16, 64);
        acc.y += __shfl_xor(acc.y, 16, 64);
        acc.z += __shfl_xor(acc.z, 16, 64);
        acc.w += __shfl_xor(acc.w, 16, 64);
        acc.x += __shfl_xor(acc.x, 32, 64);
        acc.y += __shfl_xor(acc.y, 32, 64);
        acc.z += __shfl_xor(acc.z, 32, 64);
        acc.w += __shfl_xor(acc.w, 32, 64);
    }
    if (g == 0)
        *(float4*)(T + (size_t)wid * 64 + coff) = acc;
}

__global__ void __launch_bounds__(256)
proj_kernel(const float* __restrict__ T,
            const float* __restrict__ W,
            const float* __restrict__ bias,
            float* __restrict__ out, int M) {
    __shared__ float lds_w[64][128];
    __shared__ float lds_t[64][TM + 4];   // [k][row]

    int tid  = threadIdx.x;
    long row0 = (long)blockIdx.x * TM;

#pragma unroll
    for (int i = 0; i < 8; ++i) {
        int idx = tid + i * 256;
        int k   = idx >> 5;
        int ch  = idx & 31;
        float4 wv = ((const float4*)W)[idx];
        *(float4*)&lds_w[k][ch * 4] = wv;
    }
#pragma unroll
    for (int i = 0; i < 8; ++i) {
        int idx = tid + i * 256;
        int r   = idx >> 4;
        int ch  = idx & 15;
        long gr = row0 + r;
        if (gr > (long)M - 1) gr = (long)M - 1;
        float4 tv = ((const float4*)(T + gr * 64))[ch];
        lds_t[ch * 4 + 0][r] = tv.x;
        lds_t[ch * 4 + 1][r] = tv.y;
        lds_t[ch * 4 + 2][r] = tv.z;
        lds_t[ch * 4 + 3][r] = tv.w;
    }
    __syncthreads();

    int c0 = (tid & 15) * 8;
    int r0 = (tid >> 4) * 8;

    float acc[8][8];
#pragma unroll
    for (int r = 0; r < 8; ++r)
#pragma unroll
        for (int c = 0; c < 8; ++c) acc[r][c] = 0.f;

#pragma unroll 4
    for (int k = 0; k < 64; ++k) {
        float4 ta = *(const float4*)&lds_t[k][r0];
        float4 tb = *(const float4*)&lds_t[k][r0 + 4];
        float4 wa = *(const float4*)&lds_w[k][c0];
        float4 wb = *(const float4*)&lds_w[k][c0 + 4];
        float t[8] = {ta.x, ta.y, ta.z, ta.w, tb.x, tb.y, tb.z, tb.w};
        float w[8] = {wa.x, wa.y, wa.z, wa.w, wb.x, wb.y, wb.z, wb.w};
#pragma unroll
        for (int r = 0; r < 8; ++r)
#pragma unroll
            for (int c = 0; c < 8; ++c)
                acc[r][c] = fmaf(t[r], w[c], acc[r][c]);
    }

    float4 bva = *(const float4*)&bias[c0];
    float4 bvb = *(const float4*)&bias[c0 + 4];
#pragma unroll
    for (int r = 0; r < 8; ++r) {
        long row = row0 + r0 + r;
        if (row < M) {
            float4 o0, o1;
            o0.x = acc[r][0] + bva.x;
            o0.y = acc[r][1] + bva.y;
            o0.z = acc[r][2] + bva.z;
            o0.w = acc[r][3] + bva.w;
            o1.x = acc[r][4] + bvb.x;
            o1.y = acc[r][5] + bvb.y;
            o1.z = acc[r][6] + bvb.z;
            o1.w = acc[r][7] + bvb.w;
            *(float4*)&out[row * 128 + c0]     = o0;
            *(float4*)&out[row * 128 + c0 + 4] = o1;
        }
    }
}

extern "C" void kernel_launch(void* const* d_in, const int* in_sizes, int n_in,
                              void* d_out, int out_size, void* d_ws, size_t ws_size,
                              hipStream_t stream) {
    const float* feat = (const float*)d_in[0];   // [N_ATOMS, 64] f32
    const int*   aidx = (const int*)d_in[1];     // [E] int
    const int*   dids = (const int*)d_in[2];     // [E] int (sorted)
    const float* W    = (const float*)d_in[4];   // [64, 128] f32
    const float* bias = (const float*)d_in[5];   // [128] f32
    float*       out  = (float*)d_out;           // [M, 128] f32

    int E = in_sizes[1];
    int M = out_size / 128;
    long nfeat = in_sizes[0];                    // N_ATOMS * 64 elements

    size_t fh_bytes = (size_t)nfeat * 2;               // fp16 features
    size_t th_bytes = (size_t)M * 64 * 2;              // fp16 T
    size_t bbytes   = 2 * (size_t)M * sizeof(int);     // bounds

    int waves_blocks = (int)(((size_t)M * 64 + 255) / 256);

    if (ws_size >= fh_bytes + th_bytes + bbytes) {
        // -------- fp16 path --------
        __half* feat_h = (__half*)d_ws;
        __half* T_h    = (__half*)((char*)d_ws + fh_bytes);
        int* starts    = (int*)((char*)d_ws + fh_bytes + th_bytes);
        int* ends      = starts + M;

        hipMemsetAsync(starts, 0xFF, bbytes, stream);
        conv_bounds_kernel<<<4096, 256, 0, stream>>>(feat, feat_h, nfeat / 4,
                                                     dids, starts, ends, E);
        seg_sum_h_kernel<<<waves_blocks, 256, 0, stream>>>(feat_h, aidx,
                                                           starts, ends, T_h, M);
        proj_h_kernel<<<(M + TM - 1) / TM, 256, 0, stream>>>(T_h, W, bias, out, M);
    } else {
        // -------- exact f32 fallback (round-3 verified) --------
        float* T = (float*)d_ws;
        size_t tbytes = (size_t)M * 64 * sizeof(float);
        int* starts;
        if (ws_size >= tbytes + bbytes) {
            starts = (int*)((char*)d_ws + tbytes);
        } else {
            starts = (int*)((char*)d_out + (size_t)out_size * sizeof(float) - bbytes);
        }
        int* ends = starts + M;

        hipMemsetAsync(starts, 0xFF, bbytes, stream);
        bounds_kernel<<<(E + 255) / 256, 256, 0, stream>>>(dids, starts, ends, E);
        seg_sum_kernel<<<waves_blocks, 256, 0, stream>>>(feat, aidx, starts, ends, T, M);
        proj_kernel<<<(M + TM - 1) / TM, 256, 0, stream>>>(T, W, bias, out, M);
    }
}